// Round 16
// baseline (187.018 us; speedup 1.0000x reference)
//
#include <hip/hip_runtime.h>

#define KDIM    1200
#define NBITS   2400
#define BATCHN  16384
#define NPAR    1200
#define KP      1216            // K padded to 19*64
#define KSL     19              // 64-wide k-slices
// fallback-path constants
#define WPAD    20
#define ROWS    16

typedef int i32x4 __attribute__((ext_vector_type(4)));

// ---------- conv_m: m int32 -> A_i8 [BATCHN][KP] + identity half of out ----------
__global__ __launch_bounds__(256) void conv_m(const int* __restrict__ m,
                                              unsigned char* __restrict__ A,
                                              float* __restrict__ out) {
    int gid = blockIdx.x * 256 + threadIdx.x;     // BATCHN*304 threads, exact
    int row = gid / 304;
    int seg = gid - row * 304;                    // dword index within padded row
    unsigned char* ap = A + (size_t)row * KP + seg * 4;
    if (seg < 300) {
        int4 v = *(const int4*)(m + (size_t)row * KDIM + seg * 4);
        unsigned b0 = v.x != 0, b1 = v.y != 0, b2 = v.z != 0, b3 = v.w != 0;
        *(unsigned*)ap = b0 | (b1 << 8) | (b2 << 16) | (b3 << 24);
        float4 f;
        f.x = __uint_as_float(0x3f800000u | (b0 << 31));
        f.y = __uint_as_float(0x3f800000u | (b1 << 31));
        f.z = __uint_as_float(0x3f800000u | (b2 << 31));
        f.w = __uint_as_float(0x3f800000u | (b3 << 31));
        *(float4*)(out + (size_t)row * NBITS + seg * 4) = f;
    } else {
        *(unsigned*)ap = 0u;                      // K pad
    }
}

// ---------- conv_g: G parity rows (1200..2399) f32 -> Gp_i8 [NPAR][KP] ----------
__global__ __launch_bounds__(256) void conv_g(const float* __restrict__ G,
                                              unsigned char* __restrict__ Bm) {
    int gid = blockIdx.x * 256 + threadIdx.x;     // NPAR*304 threads, exact
    int n   = gid / 304;
    int seg = gid - n * 304;
    unsigned char* bp = Bm + (size_t)n * KP + seg * 4;
    if (seg < 300) {
        float4 v = *(const float4*)(G + (size_t)(NPAR + n) * KDIM + seg * 4);
        unsigned b0 = v.x != 0.0f, b1 = v.y != 0.0f, b2 = v.z != 0.0f, b3 = v.w != 0.0f;
        *(unsigned*)bp = b0 | (b1 << 8) | (b2 << 16) | (b3 << 24);
    } else {
        *(unsigned*)bp = 0u;
    }
}

// ---------- gemm_i8: parity half via MFMA, 5 N-tiles in flight ----------
// grid (256, 3): x = M-panel (64 rows), y = N-panel (400 cols = 25 16-wide tiles).
__global__ __launch_bounds__(256) void gemm_i8(const unsigned char* __restrict__ A,
                                               const unsigned char* __restrict__ Bm,
                                               float* __restrict__ out) {
    const int l  = threadIdx.x & 63;
    const int w  = threadIdx.x >> 6;              // wave 0..3 -> M sub-tile
    const int by = blockIdx.x;                    // 0..255
    const int bx = blockIdx.y;                    // 0..2

    // A fragments for this wave's 16 rows, all 19 k-slices (76 VGPRs), read once
    const int rowA = by * 64 + w * 16 + (l & 15);
    const int kof  = (l >> 4) * 16;               // 16-byte k-group within a slice
    const i32x4* ap = (const i32x4*)(A + (size_t)rowA * KP + kof);
    i32x4 a[KSL];
    #pragma unroll
    for (int s = 0; s < KSL; ++s) a[s] = ap[4 * s];

    const int crow0 = by * 64 + w * 16 + (l >> 4) * 4;   // C/D: row = 4*(l>>4)+reg
    float* obase = out + (size_t)crow0 * NBITS + NPAR;   // column added per-store below
    const int cl = l & 15;                               // B/C col-within-tile for this lane

    #pragma unroll 1
    for (int tg = 0; tg < 5; ++tg) {
        // 5 tiles of 16 cols; 5 independent MFMA chains for ILP
        const int colbase = bx * 400 + tg * 80;
        const unsigned char* b0 = Bm + (size_t)(colbase + cl +  0) * KP + kof;
        const unsigned char* b1 = Bm + (size_t)(colbase + cl + 16) * KP + kof;
        const unsigned char* b2 = Bm + (size_t)(colbase + cl + 32) * KP + kof;
        const unsigned char* b3 = Bm + (size_t)(colbase + cl + 48) * KP + kof;
        const unsigned char* b4 = Bm + (size_t)(colbase + cl + 64) * KP + kof;
        i32x4 c0 = {0,0,0,0}, c1 = {0,0,0,0}, c2 = {0,0,0,0},
              c3 = {0,0,0,0}, c4 = {0,0,0,0};
        #pragma unroll
        for (int s = 0; s < KSL; ++s) {
            c0 = __builtin_amdgcn_mfma_i32_16x16x64_i8(a[s], *(const i32x4*)(b0 + s * 64), c0, 0, 0, 0);
            c1 = __builtin_amdgcn_mfma_i32_16x16x64_i8(a[s], *(const i32x4*)(b1 + s * 64), c1, 0, 0, 0);
            c2 = __builtin_amdgcn_mfma_i32_16x16x64_i8(a[s], *(const i32x4*)(b2 + s * 64), c2, 0, 0, 0);
            c3 = __builtin_amdgcn_mfma_i32_16x16x64_i8(a[s], *(const i32x4*)(b3 + s * 64), c3, 0, 0, 0);
            c4 = __builtin_amdgcn_mfma_i32_16x16x64_i8(a[s], *(const i32x4*)(b4 + s * 64), c4, 0, 0, 0);
        }
        #pragma unroll
        for (int r = 0; r < 4; ++r) {
            float* orow = obase + (size_t)r * NBITS + colbase;   // panel offset restored
            orow[cl +  0] = __uint_as_float(0x3f800000u | ((unsigned)(c0[r] & 1) << 31));
            orow[cl + 16] = __uint_as_float(0x3f800000u | ((unsigned)(c1[r] & 1) << 31));
            orow[cl + 32] = __uint_as_float(0x3f800000u | ((unsigned)(c2[r] & 1) << 31));
            orow[cl + 48] = __uint_as_float(0x3f800000u | ((unsigned)(c3[r] & 1) << 31));
            orow[cl + 64] = __uint_as_float(0x3f800000u | ((unsigned)(c4[r] & 1) << 31));
        }
        __syncthreads();   // keep the 4 waves lockstep: shared B frags hit L1
    }
}

// ============== fallback bit-slice path (r7-proven) ==============

__global__ __launch_bounds__(256) void pack_rows_int(const int* __restrict__ src,
                                                     unsigned long long* __restrict__ dst) {
    int gtid = blockIdx.x * blockDim.x + threadIdx.x;
    int wave = gtid >> 6, lane = gtid & 63;
    if (wave >= BATCHN) return;
    const int* row = src + (size_t)wave * KDIM;
    unsigned long long* orow = dst + (size_t)wave * WPAD;
    #pragma unroll
    for (int j = 0; j < WPAD; ++j) {
        int idx = j * 64 + lane;
        int v = (idx < KDIM) ? row[idx] : 0;
        unsigned long long mask = __ballot(v != 0);
        if (lane == 0) orow[j] = mask;
    }
}

__global__ __launch_bounds__(256) void pack_g(const float* __restrict__ G,
                                              unsigned long long* __restrict__ gp) {
    int gtid = blockIdx.x * blockDim.x + threadIdx.x;
    int wave = gtid >> 6, lane = gtid & 63;
    if (wave >= NPAR) return;
    const float* row = G + (size_t)(NPAR + wave) * KDIM;
    unsigned long long* orow = gp + (size_t)wave * WPAD;
    #pragma unroll
    for (int j = 0; j < WPAD; ++j) {
        int idx = j * 64 + lane;
        float v = (idx < KDIM) ? row[idx] : 0.0f;
        unsigned long long mask = __ballot(v != 0.0f);
        if (lane == 0) orow[j] = mask;
    }
}

__global__ __launch_bounds__(256, 4) void ldpc_encode_fb(const unsigned long long* __restrict__ mp,
                                                         const unsigned long long* __restrict__ gp,
                                                         float* __restrict__ out) {
    const int tid = threadIdx.x;
    const int n   = blockIdx.x * 256 + tid;
    const bool nv = (n < NPAR);
    unsigned g[38];
    {
        const uint4* gr = (const uint4*)(gp + (size_t)(nv ? n : 0) * WPAD);
        #pragma unroll
        for (int j = 0; j < 9; ++j) {
            uint4 v = gr[j];
            g[4*j] = v.x; g[4*j+1] = v.y; g[4*j+2] = v.z; g[4*j+3] = v.w;
        }
        uint4 v9 = gr[9];
        g[36] = v9.x; g[37] = v9.y;
    }
    const int row0 = blockIdx.y * ROWS;
    const uint4* mr = (const uint4*)(mp + (size_t)row0 * WPAD);
    const int idw = blockIdx.x * 8 + (tid >> 5);
    float* ob = out + (size_t)row0 * NBITS;
    #pragma unroll 1
    for (int i = 0; i < ROWS; ++i) {
        uint4 t[10];
        #pragma unroll
        for (int j = 0; j < 10; ++j) t[j] = mr[j];
        unsigned idb = ((const unsigned*)mr)[idw];
        unsigned p = 0;
        #pragma unroll
        for (int j = 0; j < 9; ++j) {
            p ^= t[j].x & g[4*j];
            p ^= t[j].y & g[4*j+1];
            p ^= t[j].z & g[4*j+2];
            p ^= t[j].w & g[4*j+3];
        }
        p ^= t[9].x & g[36];
        p ^= t[9].y & g[37];
        if (nv) {
            ob[n]        = __uint_as_float(0x3f800000u | (((idb >> (tid & 31)) & 1u) << 31));
            ob[NPAR + n] = __uint_as_float(0x3f800000u | ((unsigned)__popc(p) << 31));
        }
        mr += WPAD / 2;
        ob += NBITS;
    }
}

__global__ __launch_bounds__(256) void ldpc_naive(const int* __restrict__ m,
                                                  const float* __restrict__ G,
                                                  float* __restrict__ out) {
    long long idx = (long long)blockIdx.x * blockDim.x + threadIdx.x;
    if (idx >= (long long)BATCHN * NBITS) return;
    int b = (int)(idx / NBITS);
    int n = (int)(idx % NBITS);
    int acc = 0;
    const int*   mr = m + (size_t)b * KDIM;
    const float* gr = G + (size_t)n * KDIM;
    for (int k = 0; k < KDIM; ++k)
        acc ^= (mr[k] & (gr[k] != 0.0f ? 1 : 0));
    out[idx] = 1.0f - 2.0f * (float)acc;
}

// ============== launcher ==============

extern "C" void kernel_launch(void* const* d_in, const int* in_sizes, int n_in,
                              void* d_out, int out_size, void* d_ws, size_t ws_size,
                              hipStream_t stream) {
    const int*   m = (const int*)d_in[0];    // [BATCHN, KDIM] int32 (0/1)
    const float* G = (const float*)d_in[1];  // [NBITS, KDIM]  f32, top 1200x1200 = I
    float* out = (float*)d_out;              // [BATCHN, NBITS] f32

    const size_t sz_A  = (size_t)BATCHN * KP;            // 19,922,944
    const size_t sz_B  = (size_t)NPAR * KP;              //  1,459,200
    const size_t need_mfma = sz_A + sz_B;                // ~20.4 MiB
    const size_t need_fb = ((size_t)BATCHN + NPAR) * WPAD * sizeof(unsigned long long);

    if (ws_size >= need_mfma) {
        unsigned char* A  = (unsigned char*)d_ws;
        unsigned char* Bm = A + sz_A;

        conv_g<<<(NPAR * 304) / 256, 256, 0, stream>>>(G, Bm);
        conv_m<<<(BATCHN * 304) / 256, 256, 0, stream>>>(m, A, out);
        dim3 grid(BATCHN / 64, 3);                       // (256, 3)
        gemm_i8<<<grid, 256, 0, stream>>>(A, Bm, out);
    } else if (ws_size >= need_fb) {
        unsigned long long* mp = (unsigned long long*)d_ws;
        unsigned long long* gp = mp + (size_t)BATCHN * WPAD;
        pack_g       <<<(NPAR * 64) / 256, 256, 0, stream>>>(G, gp);
        pack_rows_int<<<(BATCHN * 64) / 256, 256, 0, stream>>>(m, mp);
        dim3 grid((NPAR + 255) / 256, BATCHN / ROWS);
        ldpc_encode_fb<<<grid, 256, 0, stream>>>(mp, gp, out);
    } else {
        long long total = (long long)BATCHN * NBITS;
        ldpc_naive<<<(int)((total + 255) / 256), 256, 0, stream>>>(m, G, out);
    }
}

// Round 17
// 111.236 us; speedup vs baseline: 1.6813x; 1.6813x over previous
//
#include <hip/hip_runtime.h>

#define KDIM    1200
#define NBITS   2400
#define BATCHN  16384
#define NPAR    1200
#define KP      1216            // K padded to 19*64
#define KSL     19              // 64-wide k-slices
// fallback-path constants
#define WPAD    20
#define ROWS    16

typedef int i32x4 __attribute__((ext_vector_type(4)));

// ---------- conv_m: m int32 -> A_i8 [BATCHN][KP] + identity half of out ----------
__global__ __launch_bounds__(256) void conv_m(const int* __restrict__ m,
                                              unsigned char* __restrict__ A,
                                              float* __restrict__ out) {
    int gid = blockIdx.x * 256 + threadIdx.x;     // BATCHN*304 threads, exact
    int row = gid / 304;
    int seg = gid - row * 304;                    // dword index within padded row
    unsigned char* ap = A + (size_t)row * KP + seg * 4;
    if (seg < 300) {
        int4 v = *(const int4*)(m + (size_t)row * KDIM + seg * 4);
        unsigned b0 = v.x != 0, b1 = v.y != 0, b2 = v.z != 0, b3 = v.w != 0;
        *(unsigned*)ap = b0 | (b1 << 8) | (b2 << 16) | (b3 << 24);
        float4 f;
        f.x = __uint_as_float(0x3f800000u | (b0 << 31));
        f.y = __uint_as_float(0x3f800000u | (b1 << 31));
        f.z = __uint_as_float(0x3f800000u | (b2 << 31));
        f.w = __uint_as_float(0x3f800000u | (b3 << 31));
        *(float4*)(out + (size_t)row * NBITS + seg * 4) = f;
    } else {
        *(unsigned*)ap = 0u;                      // K pad
    }
}

// ---------- conv_g: G parity rows (1200..2399) f32 -> Gp_i8 [NPAR][KP] ----------
__global__ __launch_bounds__(256) void conv_g(const float* __restrict__ G,
                                              unsigned char* __restrict__ Bm) {
    int gid = blockIdx.x * 256 + threadIdx.x;     // NPAR*304 threads, exact
    int n   = gid / 304;
    int seg = gid - n * 304;
    unsigned char* bp = Bm + (size_t)n * KP + seg * 4;
    if (seg < 300) {
        float4 v = *(const float4*)(G + (size_t)(NPAR + n) * KDIM + seg * 4);
        unsigned b0 = v.x != 0.0f, b1 = v.y != 0.0f, b2 = v.z != 0.0f, b3 = v.w != 0.0f;
        *(unsigned*)bp = b0 | (b1 << 8) | (b2 << 16) | (b3 << 24);
    } else {
        *(unsigned*)bp = 0u;
    }
}

// ---------- gemm_i8: register-tile GEMM, K-outer ----------
// grid (128, 15): x = M-panel (128 rows, 4 waves x 32), y = N-panel (80 cols).
// Wave register tile: 2 M-tiles x 5 N-tiles; per k-slice: 7 loads, 10 MFMAs.
__global__ __launch_bounds__(256) void gemm_i8(const unsigned char* __restrict__ A,
                                               const unsigned char* __restrict__ Bm,
                                               float* __restrict__ out) {
    const int l   = threadIdx.x & 63;
    const int w   = threadIdx.x >> 6;             // wave 0..3 -> +32 rows each
    const int m0  = blockIdx.x * 128 + w * 32;    // wave's first row
    const int n0  = blockIdx.y * 80;              // block's first col
    const int cl  = l & 15;
    const int kof = (l >> 4) * 16;                // 16-byte k-group within a slice

    const unsigned char* a0p = A + (size_t)(m0 + cl) * KP + kof;        // M-tile 0
    const unsigned char* a1p = A + (size_t)(m0 + 16 + cl) * KP + kof;   // M-tile 1
    const unsigned char* b0p = Bm + (size_t)(n0 + cl +  0) * KP + kof;
    const unsigned char* b1p = Bm + (size_t)(n0 + cl + 16) * KP + kof;
    const unsigned char* b2p = Bm + (size_t)(n0 + cl + 32) * KP + kof;
    const unsigned char* b3p = Bm + (size_t)(n0 + cl + 48) * KP + kof;
    const unsigned char* b4p = Bm + (size_t)(n0 + cl + 64) * KP + kof;

    i32x4 c00 = {0,0,0,0}, c01 = {0,0,0,0}, c02 = {0,0,0,0}, c03 = {0,0,0,0}, c04 = {0,0,0,0};
    i32x4 c10 = {0,0,0,0}, c11 = {0,0,0,0}, c12 = {0,0,0,0}, c13 = {0,0,0,0}, c14 = {0,0,0,0};

    #pragma unroll
    for (int s = 0; s < KSL; ++s) {
        const int o = s * 64;
        i32x4 af0 = *(const i32x4*)(a0p + o);
        i32x4 af1 = *(const i32x4*)(a1p + o);
        i32x4 bf0 = *(const i32x4*)(b0p + o);
        i32x4 bf1 = *(const i32x4*)(b1p + o);
        i32x4 bf2 = *(const i32x4*)(b2p + o);
        i32x4 bf3 = *(const i32x4*)(b3p + o);
        i32x4 bf4 = *(const i32x4*)(b4p + o);
        c00 = __builtin_amdgcn_mfma_i32_16x16x64_i8(af0, bf0, c00, 0, 0, 0);
        c10 = __builtin_amdgcn_mfma_i32_16x16x64_i8(af1, bf0, c10, 0, 0, 0);
        c01 = __builtin_amdgcn_mfma_i32_16x16x64_i8(af0, bf1, c01, 0, 0, 0);
        c11 = __builtin_amdgcn_mfma_i32_16x16x64_i8(af1, bf1, c11, 0, 0, 0);
        c02 = __builtin_amdgcn_mfma_i32_16x16x64_i8(af0, bf2, c02, 0, 0, 0);
        c12 = __builtin_amdgcn_mfma_i32_16x16x64_i8(af1, bf2, c12, 0, 0, 0);
        c03 = __builtin_amdgcn_mfma_i32_16x16x64_i8(af0, bf3, c03, 0, 0, 0);
        c13 = __builtin_amdgcn_mfma_i32_16x16x64_i8(af1, bf3, c13, 0, 0, 0);
        c04 = __builtin_amdgcn_mfma_i32_16x16x64_i8(af0, bf4, c04, 0, 0, 0);
        c14 = __builtin_amdgcn_mfma_i32_16x16x64_i8(af1, bf4, c14, 0, 0, 0);
    }

    // C/D layout: col = l&15, row = 4*(l>>4) + reg
    #define STORE_TILE(cc, mi, ni)                                                    \
        {                                                                             \
            float* orow = out + (size_t)(m0 + (mi)*16 + (l >> 4) * 4) * NBITS         \
                        + NPAR + n0 + (ni)*16 + cl;                                   \
            orow[0]                  = __uint_as_float(0x3f800000u | ((unsigned)((cc)[0] & 1) << 31)); \
            orow[(size_t)1 * NBITS]  = __uint_as_float(0x3f800000u | ((unsigned)((cc)[1] & 1) << 31)); \
            orow[(size_t)2 * NBITS]  = __uint_as_float(0x3f800000u | ((unsigned)((cc)[2] & 1) << 31)); \
            orow[(size_t)3 * NBITS]  = __uint_as_float(0x3f800000u | ((unsigned)((cc)[3] & 1) << 31)); \
        }
    STORE_TILE(c00, 0, 0) STORE_TILE(c01, 0, 1) STORE_TILE(c02, 0, 2)
    STORE_TILE(c03, 0, 3) STORE_TILE(c04, 0, 4)
    STORE_TILE(c10, 1, 0) STORE_TILE(c11, 1, 1) STORE_TILE(c12, 1, 2)
    STORE_TILE(c13, 1, 3) STORE_TILE(c14, 1, 4)
    #undef STORE_TILE
}

// ============== fallback bit-slice path (r7-proven) ==============

__global__ __launch_bounds__(256) void pack_rows_int(const int* __restrict__ src,
                                                     unsigned long long* __restrict__ dst) {
    int gtid = blockIdx.x * blockDim.x + threadIdx.x;
    int wave = gtid >> 6, lane = gtid & 63;
    if (wave >= BATCHN) return;
    const int* row = src + (size_t)wave * KDIM;
    unsigned long long* orow = dst + (size_t)wave * WPAD;
    #pragma unroll
    for (int j = 0; j < WPAD; ++j) {
        int idx = j * 64 + lane;
        int v = (idx < KDIM) ? row[idx] : 0;
        unsigned long long mask = __ballot(v != 0);
        if (lane == 0) orow[j] = mask;
    }
}

__global__ __launch_bounds__(256) void pack_g(const float* __restrict__ G,
                                              unsigned long long* __restrict__ gp) {
    int gtid = blockIdx.x * blockDim.x + threadIdx.x;
    int wave = gtid >> 6, lane = gtid & 63;
    if (wave >= NPAR) return;
    const float* row = G + (size_t)(NPAR + wave) * KDIM;
    unsigned long long* orow = gp + (size_t)wave * WPAD;
    #pragma unroll
    for (int j = 0; j < WPAD; ++j) {
        int idx = j * 64 + lane;
        float v = (idx < KDIM) ? row[idx] : 0.0f;
        unsigned long long mask = __ballot(v != 0.0f);
        if (lane == 0) orow[j] = mask;
    }
}

__global__ __launch_bounds__(256, 4) void ldpc_encode_fb(const unsigned long long* __restrict__ mp,
                                                         const unsigned long long* __restrict__ gp,
                                                         float* __restrict__ out) {
    const int tid = threadIdx.x;
    const int n   = blockIdx.x * 256 + tid;
    const bool nv = (n < NPAR);
    unsigned g[38];
    {
        const uint4* gr = (const uint4*)(gp + (size_t)(nv ? n : 0) * WPAD);
        #pragma unroll
        for (int j = 0; j < 9; ++j) {
            uint4 v = gr[j];
            g[4*j] = v.x; g[4*j+1] = v.y; g[4*j+2] = v.z; g[4*j+3] = v.w;
        }
        uint4 v9 = gr[9];
        g[36] = v9.x; g[37] = v9.y;
    }
    const int row0 = blockIdx.y * ROWS;
    const uint4* mr = (const uint4*)(mp + (size_t)row0 * WPAD);
    const int idw = blockIdx.x * 8 + (tid >> 5);
    float* ob = out + (size_t)row0 * NBITS;
    #pragma unroll 1
    for (int i = 0; i < ROWS; ++i) {
        uint4 t[10];
        #pragma unroll
        for (int j = 0; j < 10; ++j) t[j] = mr[j];
        unsigned idb = ((const unsigned*)mr)[idw];
        unsigned p = 0;
        #pragma unroll
        for (int j = 0; j < 9; ++j) {
            p ^= t[j].x & g[4*j];
            p ^= t[j].y & g[4*j+1];
            p ^= t[j].z & g[4*j+2];
            p ^= t[j].w & g[4*j+3];
        }
        p ^= t[9].x & g[36];
        p ^= t[9].y & g[37];
        if (nv) {
            ob[n]        = __uint_as_float(0x3f800000u | (((idb >> (tid & 31)) & 1u) << 31));
            ob[NPAR + n] = __uint_as_float(0x3f800000u | ((unsigned)__popc(p) << 31));
        }
        mr += WPAD / 2;
        ob += NBITS;
    }
}

__global__ __launch_bounds__(256) void ldpc_naive(const int* __restrict__ m,
                                                  const float* __restrict__ G,
                                                  float* __restrict__ out) {
    long long idx = (long long)blockIdx.x * blockDim.x + threadIdx.x;
    if (idx >= (long long)BATCHN * NBITS) return;
    int b = (int)(idx / NBITS);
    int n = (int)(idx % NBITS);
    int acc = 0;
    const int*   mr = m + (size_t)b * KDIM;
    const float* gr = G + (size_t)n * KDIM;
    for (int k = 0; k < KDIM; ++k)
        acc ^= (mr[k] & (gr[k] != 0.0f ? 1 : 0));
    out[idx] = 1.0f - 2.0f * (float)acc;
}

// ============== launcher ==============

extern "C" void kernel_launch(void* const* d_in, const int* in_sizes, int n_in,
                              void* d_out, int out_size, void* d_ws, size_t ws_size,
                              hipStream_t stream) {
    const int*   m = (const int*)d_in[0];    // [BATCHN, KDIM] int32 (0/1)
    const float* G = (const float*)d_in[1];  // [NBITS, KDIM]  f32, top 1200x1200 = I
    float* out = (float*)d_out;              // [BATCHN, NBITS] f32

    const size_t sz_A  = (size_t)BATCHN * KP;            // 19,922,944
    const size_t sz_B  = (size_t)NPAR * KP;              //  1,459,200
    const size_t need_mfma = sz_A + sz_B;                // ~20.4 MiB
    const size_t need_fb = ((size_t)BATCHN + NPAR) * WPAD * sizeof(unsigned long long);

    if (ws_size >= need_mfma) {
        unsigned char* A  = (unsigned char*)d_ws;
        unsigned char* Bm = A + sz_A;

        conv_g<<<(NPAR * 304) / 256, 256, 0, stream>>>(G, Bm);
        conv_m<<<(BATCHN * 304) / 256, 256, 0, stream>>>(m, A, out);
        dim3 grid(BATCHN / 128, 15);                     // (128, 15) = 1920 blocks
        gemm_i8<<<grid, 256, 0, stream>>>(A, Bm, out);
    } else if (ws_size >= need_fb) {
        unsigned long long* mp = (unsigned long long*)d_ws;
        unsigned long long* gp = mp + (size_t)BATCHN * WPAD;
        pack_g       <<<(NPAR * 64) / 256, 256, 0, stream>>>(G, gp);
        pack_rows_int<<<(BATCHN * 64) / 256, 256, 0, stream>>>(m, mp);
        dim3 grid((NPAR + 255) / 256, BATCHN / ROWS);
        ldpc_encode_fb<<<grid, 256, 0, stream>>>(mp, gp, out);
    } else {
        long long total = (long long)BATCHN * NBITS;
        ldpc_naive<<<(int)((total + 255) / 256), 256, 0, stream>>>(m, G, out);
    }
}